// Round 17
// baseline (164.682 us; speedup 1.0000x reference)
//
#include <hip/hip_runtime.h>

#define B_ 32
#define C_ 256
#define D_ 128
#define HH 56
#define WW 56
#define N_ 3136
#define KSPLIT 7
#define KRANGE 448   // n per K-split in k2: 14 steps of 32

typedef float f32x4 __attribute__((ext_vector_type(4)));
typedef short s16x8 __attribute__((ext_vector_type(8)));
typedef unsigned short u16x8 __attribute__((ext_vector_type(8)));

// Row swizzle for [R][32-bf16] LDS tiles (64B rows = 4x16B units).
__device__ __forceinline__ int swz4(int r){
  return (r & 3) ^ (((r >> 2) & 1) << 1) ^ ((r >> 3) & 1);
}
__device__ __forceinline__ unsigned short f2bf(float f){
  unsigned u = __float_as_uint(f);
  u += 0x7fffu + ((u >> 16) & 1u);           // RNE
  return (unsigned short)(u >> 16);
}
__device__ __forceinline__ float bf2f(unsigned short h){
  return __uint_as_float(((unsigned)h) << 16);
}
__device__ __forceinline__ float elu1(float v){
  return v > 0.f ? v + 1.f : __expf(v);      // elu(v)+1
}
// HW packed f32x2 -> bf16x2 (RNE), 1 instr for 2 values.
__device__ __forceinline__ unsigned cvtpk(float lo, float hi){
  unsigned r;
  asm("v_cvt_pk_bf16_f32 %0, %1, %2" : "=v"(r) : "v"(lo), "v"(hi));
  return r;
}

// Stage [R rows][32 bf16] bf16-global -> swizzled LDS via global_load_lds.
// 256-thread variant.
template<int R>
__device__ __forceinline__ void stage_glds(const unsigned short* gp, int ld, char* lds){
  const int tid = threadIdx.x;
  const int wid = tid >> 6;
#pragma unroll
  for (int q = 0; q < R/64; ++q){
    const int slot = q*256 + tid;            // = r*4 + unit
    const int r = slot >> 2, gi = slot & 3;
    const int u = gi ^ swz4(r);
    const unsigned short* ga = gp + r*ld + u*8;
    char* lb = lds + (q*256 + wid*64)*16;    // wave-uniform LDS base
    __builtin_amdgcn_global_load_lds(
        (__attribute__((address_space(1))) void*)ga,
        (__attribute__((address_space(3))) void*)lb, 16, 0, 0);
  }
}

__device__ __forceinline__ s16x8 ldsfrag(const char* lds, int r, int g){
  return *(const s16x8*)(lds + r*64 + ((g ^ swz4(r)) << 4));
}

// ---------------------------------------------------------------------------
// K0w: W fp32 -> bf16.
// ---------------------------------------------------------------------------
__global__ __launch_bounds__(256) void k0_w(
    const float* __restrict__ w, unsigned short* __restrict__ wb)
{
  const int i = blockIdx.x*256 + threadIdx.x;   // 16384 float4s
  float4 v = *(const float4*)(w + (size_t)i*4);
  uint2 h = {cvtpk(v.x, v.y), cvtpk(v.z, v.w)};
  *(uint2*)(wb + (size_t)i*4) = h;
}

// ---------------------------------------------------------------------------
// K1 v3: qk = elu(W.x + b)+1. MFMA GEMM M=256(o) x BN=64(n) x K=256(c),
// LDS-FREE: both operands loaded per-lane directly into fragments.
// r10-r16 lesson: any {load -> barrier -> scatter -> barrier -> MFMA} chain
// for this transpose-feed pins at ~58-66us regardless of TLP/MLP. Here:
// A-frag = 16B contiguous load from wb (L2-resident); B-frag = 8 scalar x
// loads (16-lane groups read 64B-contiguous n segments) + cvtpk. Zero
// barriers, zero LDS, zero bank conflicts; fragments/rounding/MFMA order
// identical to r16 -> bit-identical outputs. Epilogue = proven r15 version.
// ---------------------------------------------------------------------------
__global__ __launch_bounds__(256) void k1_qk(
    const float* __restrict__ x, const unsigned short* __restrict__ wb,
    const float* __restrict__ bias,
    unsigned short* __restrict__ kbuf, unsigned short* __restrict__ qt)
{
  const int tid = threadIdx.x, lane = tid & 63, wid = tid >> 6;
  const int n0 = blockIdx.x * 64;
  const int b  = blockIdx.y;
  const int col = lane & 15, kg = lane >> 4;   // fragment row-col / K-group
  const float* xb = x + (size_t)b*C_*N_;
  const int wo = wid*64;
  f32x4 acc[4][4] = {};

  // per-thread operand bases (K-group offset folded in)
  const unsigned short* wp[4];
#pragma unroll
  for (int m = 0; m < 4; ++m)
    wp[m] = wb + (size_t)(wo + m*16 + col)*C_ + kg*8;
  const float* xp[4];
#pragma unroll
  for (int nf = 0; nf < 4; ++nf)
    xp[nf] = xb + (size_t)(kg*8)*N_ + n0 + nf*16 + col;

  for (int k0 = 0; k0 < C_; k0 += 32){
    s16x8 af[4];
#pragma unroll
    for (int m = 0; m < 4; ++m)
      af[m] = *(const s16x8*)(wp[m] + k0);
    s16x8 bf[4];
#pragma unroll
    for (int nf = 0; nf < 4; ++nf){
      float v[8];
#pragma unroll
      for (int j = 0; j < 8; ++j)
        v[j] = xp[nf][(size_t)(k0 + j)*N_];
      union { uint4 u; s16x8 s; } pk;
      pk.u = (uint4){cvtpk(v[0],v[1]), cvtpk(v[2],v[3]),
                     cvtpk(v[4],v[5]), cvtpk(v[6],v[7])};
      bf[nf] = pk.s;
    }
#pragma unroll
    for (int m = 0; m < 4; ++m)
#pragma unroll
      for (int nf = 0; nf < 4; ++nf)
        acc[m][nf] = __builtin_amdgcn_mfma_f32_16x16x32_bf16(af[m], bf[nf], acc[m][nf], 0, 0, 0);
  }

  const int rg = lane >> 4;
  if (wid < 2){
    // q half -> qt[b][n][d]
#pragma unroll
    for (int m = 0; m < 4; ++m){
      const int db = wo + m*16 + rg*4;
      const float b0 = bias[db], b1 = bias[db+1], b2 = bias[db+2], b3 = bias[db+3];
#pragma unroll
      for (int nf = 0; nf < 4; ++nf){
        const int n = n0 + nf*16 + col;
        f32x4 a = acc[m][nf];
        uint2 hv = {cvtpk(elu1(a[0]+b0), elu1(a[1]+b1)),
                    cvtpk(elu1(a[2]+b2), elu1(a[3]+b3))};
        *(uint2*)(qt + ((size_t)b*N_ + n)*D_ + db) = hv;
      }
    }
  } else {
    // k half -> kbuf[b][d][n]
#pragma unroll
    for (int m = 0; m < 4; ++m)
#pragma unroll
      for (int j = 0; j < 4; ++j){
        const int d = wo - 128 + m*16 + rg*4 + j;
        const float bb = bias[128 + d];
#pragma unroll
        for (int nf = 0; nf < 4; ++nf){
          const int n = n0 + nf*16 + col;
          kbuf[((size_t)b*D_ + d)*N_ + n] = f2bf(elu1(acc[m][nf][j] + bb));
        }
      }
  }
}

// ---------------------------------------------------------------------------
// K2: kv partials = sum_n k[d][n]*x[c][n] over K-split. M=128(d) x BN=256(c)
// x K=448(n). 512 threads / 8 waves. Partials stored [c][d]. Fuses kmean.
// (EXACT round-7/15 proven version.)
// ---------------------------------------------------------------------------
__global__ __launch_bounds__(512) void k2_kv(
    const unsigned short* __restrict__ kbuf, const float* __restrict__ x,
    unsigned short* __restrict__ kvp, float* __restrict__ kmp)
{
  __shared__ __align__(16) char Al[128*64];  // [128 d][32 n]
  __shared__ __align__(16) char Bl[256*64];  // [256 c][32 n]
  const int tid = threadIdx.x, lane = tid & 63, wid = tid >> 6;  // 8 waves
  const int ks = blockIdx.x;
  const int b  = blockIdx.y;
  const unsigned short* kb = kbuf + (size_t)b*D_*N_ + ks*KRANGE;
  const float* xb = x + (size_t)b*C_*N_ + ks*KRANGE;
  const int wd = (wid >> 2)*64, wc = (wid & 3)*64;
  f32x4 acc[4][4] = {};
  float kms = 0.f;
  const int sr = tid >> 2, sg = tid & 3;     // staging/kms row & unit

  for (int t = 0; t < KRANGE/32; ++t){
    __syncthreads();
    // A: 128 rows x 4 units = 512 slots, one global_load_lds per thread
    {
      const int u = sg ^ swz4(sr);
      const unsigned short* ga = kb + (size_t)sr*N_ + t*32 + u*8;
      char* lb = Al + (wid*64)*16;           // wave-uniform base; unit = tid
      __builtin_amdgcn_global_load_lds(
          (__attribute__((address_space(1))) void*)ga,
          (__attribute__((address_space(3))) void*)lb, 16, 0, 0);
    }
    // B: x[c][n] fp32 -> bf16 (cvt_pk); 256 rows x 32 n, 16 elems/thread
#pragma unroll
    for (int q = 0; q < 4; ++q){
      int idx = q*512 + tid;                 // 0..2047
      int cc = idx >> 3, n4 = (idx & 7)*4;
      float4 v = *(const float4*)(xb + (size_t)cc*N_ + t*32 + n4);
      uint2 h = {cvtpk(v.x, v.y), cvtpk(v.z, v.w)};
      *(uint2*)(Bl + cc*64 + ((n4*2) ^ (swz4(cc) << 4))) = h;
    }
    __syncthreads();
    s16x8 af[4], bv[4];
#pragma unroll
    for (int m = 0; m < 4; ++m)  af[m] = ldsfrag(Al, wd + m*16 + (lane & 15), lane >> 4);
#pragma unroll
    for (int cf = 0; cf < 4; ++cf) bv[cf] = ldsfrag(Bl, wc + cf*16 + (lane & 15), lane >> 4);
#pragma unroll
    for (int m = 0; m < 4; ++m)
#pragma unroll
      for (int cf = 0; cf < 4; ++cf)
        acc[m][cf] = __builtin_amdgcn_mfma_f32_16x16x32_bf16(af[m], bv[cf], acc[m][cf], 0, 0, 0);
    // kmean partial: thread (sr, sg) sums unit sg of k-row sr (8 bf16)
    {
      uint2 u = *(const uint2*)(Al + sr*64 + ((sg ^ swz4(sr)) << 4));
      uint2 u2 = *(const uint2*)(Al + sr*64 + ((sg ^ swz4(sr)) << 4) + 8);
      const unsigned ua[4] = {u.x, u.y, u2.x, u2.y};
#pragma unroll
      for (int i = 0; i < 4; ++i){
        kms += bf2f((unsigned short)(ua[i] & 0xffffu));
        kms += bf2f((unsigned short)(ua[i] >> 16));
      }
    }
  }

  kms += __shfl_xor(kms, 1);
  kms += __shfl_xor(kms, 2);
  if ((tid & 3) == 0) kmp[((size_t)b*KSPLIT + ks)*D_ + sr] = kms;

  const int col = lane & 15, rg = lane >> 4;
#pragma unroll
  for (int m = 0; m < 4; ++m){
    const int d0 = wd + m*16 + rg*4;
#pragma unroll
    for (int cf = 0; cf < 4; ++cf){
      const int c = wc + cf*16 + col;
      ushort4 hv = {f2bf(acc[m][cf][0]), f2bf(acc[m][cf][1]),
                    f2bf(acc[m][cf][2]), f2bf(acc[m][cf][3])};
      *(ushort4*)(kvp + (((size_t)b*KSPLIT + ks)*C_ + c)*D_ + d0) = hv;
    }
  }
}

// ---------------------------------------------------------------------------
// KR: kvt[b][c][d] = (1/N) * sum_ks kvp[b][ks][c][d]; km[b][d] from kmp.
// (EXACT round-7 version — proven.)
// ---------------------------------------------------------------------------
__global__ __launch_bounds__(256) void kr_reduce(
    const unsigned short* __restrict__ kvp, const float* __restrict__ kmp,
    unsigned short* __restrict__ kvt, float* __restrict__ km)
{
  const int tid = threadIdx.x;
  const int bx = blockIdx.x, b = blockIdx.y;
  const float sc = 1.0f/(float)N_;
#pragma unroll
  for (int it = 0; it < 2; ++it){
    const int idx = (bx*2 + it)*256 + tid;      // 0..4095
    const int c = idx >> 4, dq = (idx & 15)*8;
    float s[8] = {};
    for (int ks = 0; ks < KSPLIT; ++ks){
      u16x8 v = *(const u16x8*)(kvp + (((size_t)b*KSPLIT + ks)*C_ + c)*D_ + dq);
#pragma unroll
      for (int i = 0; i < 8; ++i) s[i] += bf2f(v[i]);
    }
    u16x8 h;
#pragma unroll
    for (int i = 0; i < 8; ++i) h[i] = f2bf(s[i]*sc);
    *(u16x8*)(kvt + ((size_t)b*C_ + c)*D_ + dq) = h;
  }
  if (bx == 0 && tid < D_){
    float s = 0.f;
    for (int ks = 0; ks < KSPLIT; ++ks) s += kmp[((size_t)b*KSPLIT + ks)*D_ + tid];
    km[b*D_ + tid] = s*sc;
  }
}

// ---------------------------------------------------------------------------
// K3: attn[c][n] = (sum_d kvt[c][d]*qt[n][d]) / (q.km + 1e-6), bf16 out.
// (EXACT round-7 version — proven.)
// ---------------------------------------------------------------------------
__global__ __launch_bounds__(256) void k3_attn(
    const unsigned short* __restrict__ qt, const unsigned short* __restrict__ kvt,
    const float* __restrict__ km, unsigned short* __restrict__ attn)
{
  __shared__ __align__(16) char SM[256*64 + 64*64];  // 20KB
  char* Al = SM;                                 // [256 c][32 d] (16KB)
  char* Bl = SM + 256*64;                        // [64 n][32 d]  (4KB)
  unsigned short* P = (unsigned short*)SM;       // [128][72] bf16 (18KB overlay)
  __shared__ float kms[128];
  __shared__ float dens[64];
  const int tid = threadIdx.x, lane = tid & 63, wid = tid >> 6;
  const int n0 = blockIdx.x * 64;
  const int b  = blockIdx.y;
  if (tid < 128) kms[tid] = km[b*D_ + tid];
  const unsigned short* kvb = kvt + (size_t)b*C_*D_;
  const unsigned short* qtb = qt + ((size_t)b*N_ + n0)*D_;
  const int wc = wid*64;
  f32x4 acc[4][4] = {};
  float den = 0.f;

  for (int k0 = 0; k0 < D_; k0 += 32){
    __syncthreads();
    stage_glds<256>(kvb + k0, D_, Al);
    stage_glds<64>(qtb + k0, D_, Bl);
    __syncthreads();
    s16x8 af[4], bv4[4];
#pragma unroll
    for (int m = 0; m < 4; ++m)  af[m]  = ldsfrag(Al, wc + m*16 + (lane & 15), lane >> 4);
#pragma unroll
    for (int nf = 0; nf < 4; ++nf) bv4[nf] = ldsfrag(Bl, nf*16 + (lane & 15), lane >> 4);
#pragma unroll
    for (int m = 0; m < 4; ++m)
#pragma unroll
      for (int nf = 0; nf < 4; ++nf)
        acc[m][nf] = __builtin_amdgcn_mfma_f32_16x16x32_bf16(af[m], bv4[nf], acc[m][nf], 0, 0, 0);
    {
      const int nr = tid >> 2, g = tid & 3;
      uint4 u = *(const uint4*)(Bl + nr*64 + ((g ^ swz4(nr)) << 4));
      const float* kp = kms + k0 + g*8;
      const unsigned ua[4] = {u.x, u.y, u.z, u.w};
#pragma unroll
      for (int i = 0; i < 4; ++i){
        den += bf2f((unsigned short)(ua[i] & 0xffffu)) * kp[i*2];
        den += bf2f((unsigned short)(ua[i] >> 16))     * kp[i*2 + 1];
      }
    }
  }
  den += __shfl_xor(den, 1);
  den += __shfl_xor(den, 2);
  if ((tid & 3) == 0) dens[tid >> 2] = den;
  __syncthreads();   // GEMM LDS reads done + dens visible

  const int col = lane & 15, rg = lane >> 4;
  float rdv[4];
#pragma unroll
  for (int nf = 0; nf < 4; ++nf)
    rdv[nf] = 1.0f / (dens[nf*16 + col] + 1e-6f);

#pragma unroll
  for (int h = 0; h < 2; ++h){
    if ((wid >> 1) == h){
      const int lc = wc - h*128;   // 0 or 64
#pragma unroll
      for (int m = 0; m < 4; ++m)
#pragma unroll
        for (int nf = 0; nf < 4; ++nf)
#pragma unroll
          for (int j = 0; j < 4; ++j)
            P[(lc + m*16 + rg*4 + j)*72 + (nf*16 + col)] = f2bf(acc[m][nf][j] * rdv[nf]);
    }
    __syncthreads();
#pragma unroll
    for (int p = 0; p < 4; ++p){
      const int c = (tid >> 3) + p*32, ch = tid & 7;
      u16x8 v = *(const u16x8*)(P + c*72 + ch*8);
      *(u16x8*)(attn + ((size_t)b*C_ + h*128 + c)*N_ + n0 + ch*8) = v;
    }
    __syncthreads();
  }
}

// ---------------------------------------------------------------------------
// K4: out = attn + depthwise3x3(x) + pe_b. Plane per block, 4-wide along w,
// zero-padded top/bottom LDS rows. x fp32 (EXACT round-7 proven path).
// ---------------------------------------------------------------------------
__global__ __launch_bounds__(256) void k4_pe(
    const float* __restrict__ x, const unsigned short* __restrict__ attn,
    const float* __restrict__ pw, const float* __restrict__ pb,
    float* __restrict__ out)
{
  __shared__ float xs_raw[58*56 + 8];
  float* xs = xs_raw + 4;          // slack so xs[-1] stays in-bounds
  const int tid = threadIdx.x;
  const int ch = blockIdx.x, b = blockIdx.y;
  if (tid < 14)      ((float4*)xs)[tid] = (float4){0.f,0.f,0.f,0.f};        // pad row 0
  else if (tid < 28) ((float4*)xs)[784 + tid] = (float4){0.f,0.f,0.f,0.f};  // pad row 57
  const float* xp = x + ((size_t)b*C_ + ch)*N_;
  for (int i = tid; i < 784; i += 256)
    ((float4*)xs)[14 + i] = ((const float4*)xp)[i];
  const float* wp = pw + ch*9;
  float wgt[9];
#pragma unroll
  for (int i = 0; i < 9; ++i) wgt[i] = wp[i];
  const float bias = pb[ch];
  __syncthreads();
  const unsigned short* ap = attn + ((size_t)b*C_ + ch)*N_;
  float* op = out + ((size_t)b*C_ + ch)*N_;
  for (int u = tid; u < 784; u += 256) {
    const int row = u / 14, g = u - row*14;     // output row, float4 group
    float o0 = bias, o1 = bias, o2 = bias, o3 = bias;
#pragma unroll
    for (int rr = 0; rr < 3; ++rr){
      const float* rp = xs + (row + rr)*56 + g*4;   // padded rows row..row+2
      float4 cv = *(const float4*)rp;
      float lf = (g > 0)  ? rp[-1] : 0.f;
      float rt = (g < 13) ? rp[4]  : 0.f;
      const float wl = wgt[rr*3], wc_ = wgt[rr*3+1], wr = wgt[rr*3+2];
      o0 += wl*lf   + wc_*cv.x + wr*cv.y;
      o1 += wl*cv.x + wc_*cv.y + wr*cv.z;
      o2 += wl*cv.y + wc_*cv.z + wr*cv.w;
      o3 += wl*cv.z + wc_*cv.w + wr*rt;
    }
    ushort4 av = *(const ushort4*)(ap + u*4);
    float4 ov = {o0 + bf2f(av.x), o1 + bf2f(av.y), o2 + bf2f(av.z), o3 + bf2f(av.w)};
    *(float4*)(op + u*4) = ov;
  }
}

extern "C" void kernel_launch(void* const* d_in, const int* in_sizes, int n_in,
                              void* d_out, int out_size, void* d_ws, size_t ws_size,
                              hipStream_t stream) {
  (void)in_sizes; (void)n_in; (void)out_size; (void)ws_size;
  const float* x   = (const float*)d_in[0];
  const float* qkw = (const float*)d_in[1];
  const float* qkb = (const float*)d_in[2];
  const float* pew = (const float*)d_in[3];
  const float* peb = (const float*)d_in[4];
  float* out = (float*)d_out;

  // ws layout (104.9 MB footprint, proven since round 7). slot0 (51.4 MB)
  // hosts kvp+kmp (k2->kr) then attn (k3->k4). kvt slot hosts wb then kvt.
  unsigned short* slot0 = (unsigned short*)d_ws;                // 51.4 MB scratch
  unsigned short* kbuf = slot0 + (size_t)B_*N_*C_;              // [B][128][N] bf16
  unsigned short* qt   = kbuf + (size_t)B_*D_*N_;               // [B][N][128] bf16
  unsigned short* kvt  = qt   + (size_t)B_*N_*D_;               // [B][256][128] bf16
  float* km  = (float*)(kvt + (size_t)B_*C_*D_);                // [B][128] f32
  unsigned short* wb   = kvt;                                   // [256][256] bf16 (alias)
  unsigned short* kvp  = slot0;                                 // [B][7][256][128] bf16 (alias)
  float* kmp = (float*)(kvp + (size_t)B_*KSPLIT*C_*D_);         // [B][7][128] f32 (in slot0)
  unsigned short* attn = slot0;                                 // [B][256][N] bf16 (alias)

  k0_w     <<<dim3(64),          256, 0, stream>>>(qkw, wb);
  k1_qk    <<<dim3(N_/64, B_),   256, 0, stream>>>(x, wb, qkb, kbuf, qt);
  k2_kv    <<<dim3(KSPLIT, B_),  512, 0, stream>>>(kbuf, x, kvp, kmp);
  kr_reduce<<<dim3(8, B_),       256, 0, stream>>>(kvp, kmp, kvt, km);
  k3_attn  <<<dim3(N_/64, B_),   256, 0, stream>>>(qt, kvt, km, attn);
  k4_pe    <<<dim3(C_, B_),      256, 0, stream>>>(x, attn, pew, peb, out);
}

// Round 18
// 152.479 us; speedup vs baseline: 1.0800x; 1.0800x over previous
//
#include <hip/hip_runtime.h>

#define B_ 32
#define C_ 256
#define D_ 128
#define HH 56
#define WW 56
#define N_ 3136
#define KSPLIT 7
#define KRANGE 448   // n per K-split in k2: 14 steps of 32

typedef float f32x4 __attribute__((ext_vector_type(4)));
typedef short s16x8 __attribute__((ext_vector_type(8)));
typedef unsigned short u16x8 __attribute__((ext_vector_type(8)));

// Row swizzle for [R][32-bf16] LDS tiles (64B rows = 4x16B units).
__device__ __forceinline__ int swz4(int r){
  return (r & 3) ^ (((r >> 2) & 1) << 1) ^ ((r >> 3) & 1);
}
__device__ __forceinline__ unsigned short f2bf(float f){
  unsigned u = __float_as_uint(f);
  u += 0x7fffu + ((u >> 16) & 1u);           // RNE
  return (unsigned short)(u >> 16);
}
__device__ __forceinline__ float bf2f(unsigned short h){
  return __uint_as_float(((unsigned)h) << 16);
}
__device__ __forceinline__ float elu1(float v){
  return v > 0.f ? v + 1.f : __expf(v);      // elu(v)+1
}
// HW packed f32x2 -> bf16x2 (RNE), 1 instr for 2 values.
__device__ __forceinline__ unsigned cvtpk(float lo, float hi){
  unsigned r;
  asm("v_cvt_pk_bf16_f32 %0, %1, %2" : "=v"(r) : "v"(lo), "v"(hi));
  return r;
}

// Stage [R rows][32 bf16] bf16-global -> swizzled LDS via global_load_lds.
// 256-thread variant.
template<int R>
__device__ __forceinline__ void stage_glds(const unsigned short* gp, int ld, char* lds){
  const int tid = threadIdx.x;
  const int wid = tid >> 6;
#pragma unroll
  for (int q = 0; q < R/64; ++q){
    const int slot = q*256 + tid;            // = r*4 + unit
    const int r = slot >> 2, gi = slot & 3;
    const int u = gi ^ swz4(r);
    const unsigned short* ga = gp + r*ld + u*8;
    char* lb = lds + (q*256 + wid*64)*16;    // wave-uniform LDS base
    __builtin_amdgcn_global_load_lds(
        (__attribute__((address_space(1))) void*)ga,
        (__attribute__((address_space(3))) void*)lb, 16, 0, 0);
  }
}

// 512-thread variant (one 16B DMA per thread covers 128 rows).
template<int R>
__device__ __forceinline__ void stage_glds512(const unsigned short* gp, int ld, char* lds){
  const int tid = threadIdx.x;
  const int wid = tid >> 6;
#pragma unroll
  for (int q = 0; q < R/128; ++q){
    const int slot = q*512 + tid;            // = r*4 + unit
    const int r = slot >> 2, gi = slot & 3;
    const int u = gi ^ swz4(r);
    const unsigned short* ga = gp + r*ld + u*8;
    char* lb = lds + (q*512 + wid*64)*16;    // wave-uniform LDS base
    __builtin_amdgcn_global_load_lds(
        (__attribute__((address_space(1))) void*)ga,
        (__attribute__((address_space(3))) void*)lb, 16, 0, 0);
  }
}

__device__ __forceinline__ s16x8 ldsfrag(const char* lds, int r, int g){
  return *(const s16x8*)(lds + r*64 + ((g ^ swz4(r)) << 4));
}

// ---------------------------------------------------------------------------
// K0w: W fp32 -> bf16.
// ---------------------------------------------------------------------------
__global__ __launch_bounds__(256) void k0_w(
    const float* __restrict__ w, unsigned short* __restrict__ wb)
{
  const int i = blockIdx.x*256 + threadIdx.x;   // 16384 float4s
  float4 v = *(const float4*)(w + (size_t)i*4);
  uint2 h = {cvtpk(v.x, v.y), cvtpk(v.z, v.w)};
  *(uint2*)(wb + (size_t)i*4) = h;
}

// ---------------------------------------------------------------------------
// K1 v4: qk = elu(W.x + b)+1.  MFMA GEMM M=256(o) x BN=64(n) x K=256(c).
// DOUBLE-BUFFERED, ONE barrier per K-step: iteration t = [barrier]
// [scatter x(t+1) + DMA W(t+1) into buf (t+1)&1; issue x-load t+2]
// [ds_read+MFMA from buf t&1]. Writer and reader buffers differ -> no
// intra-iteration ordering; the single barrier drains prev writes (vm+lgkm)
// and fences prev reads of the buffer being overwritten. Scatter/DMA/frag
// mechanics byte-identical to proven r16 -> bit-identical outputs.
// 512 threads / 8 waves, wave o-split 8 (acc[2][4]).
// ---------------------------------------------------------------------------
__global__ __launch_bounds__(512) void k1_qk(
    const float* __restrict__ x, const unsigned short* __restrict__ wb,
    const float* __restrict__ bias,
    unsigned short* __restrict__ kbuf, unsigned short* __restrict__ qt)
{
  __shared__ __align__(16) char Al[2][256*64];  // [256 o][32 c] bf16, swizzled
  __shared__ __align__(16) char Bl[2][64*64];   // [64 n][32 c]  bf16, swizzled
  const int tid = threadIdx.x, lane = tid & 63, wid = tid >> 6;
  const int n0 = blockIdx.x * 64;
  const int b  = blockIdx.y;
  const float* xb = x + (size_t)b*C_*N_;
  const int wo = wid*32;
  f32x4 acc[2][4] = {};
  const int cc = tid >> 4;            // 0..31 (c within K-step)
  const int nn = (tid & 15)*4;        // 0..60 (n within tile)

  // r16-identical scatter of one float4 into Bl[buf]
#define SCATTER_B(bufp, xv)                                                   \
  {                                                                           \
    const float vv[4] = {(xv).x, (xv).y, (xv).z, (xv).w};                     \
    _Pragma("unroll")                                                         \
    for (int i = 0; i < 4; ++i){                                              \
      const int r = nn + i;                                                   \
      *(unsigned short*)((bufp) + r*64 + ((cc*2) ^ (swz4(r) << 4))) = f2bf(vv[i]); \
    }                                                                         \
  }

  // prologue: fill buffer 0 with tile 0; preload x tile 1
  float4 xv0 = *(const float4*)(xb + (size_t)(0  + cc)*N_ + n0 + nn);
  float4 xcur = *(const float4*)(xb + (size_t)(32 + cc)*N_ + n0 + nn);
  SCATTER_B(Bl[0], xv0);
  stage_glds512<256>(wb + 0, C_, Al[0]);

  for (int t = 0; t < 8; ++t){
    __syncthreads();   // drains buf[(t+1)&1] prev reads + buf[t&1] writes
    if (t < 7){
      const int kn = (t + 1)*32;
      SCATTER_B(Bl[(t+1)&1], xcur);
      stage_glds512<256>(wb + kn, C_, Al[(t+1)&1]);
      if (t < 6)
        xcur = *(const float4*)(xb + (size_t)((t+2)*32 + cc)*N_ + n0 + nn);
    }
    const char* Ac = Al[t & 1];
    const char* Bc = Bl[t & 1];
    s16x8 af[2], bv4[4];
#pragma unroll
    for (int m = 0; m < 2; ++m)  af[m]  = ldsfrag(Ac, wo + m*16 + (lane & 15), lane >> 4);
#pragma unroll
    for (int nf = 0; nf < 4; ++nf) bv4[nf] = ldsfrag(Bc, nf*16 + (lane & 15), lane >> 4);
#pragma unroll
    for (int m = 0; m < 2; ++m)
#pragma unroll
      for (int nf = 0; nf < 4; ++nf)
        acc[m][nf] = __builtin_amdgcn_mfma_f32_16x16x32_bf16(af[m], bv4[nf], acc[m][nf], 0, 0, 0);
  }
#undef SCATTER_B

  const int col = lane & 15, rg = lane >> 4;
  if (wid < 4){
    // q half -> qt[b][n][d]
#pragma unroll
    for (int m = 0; m < 2; ++m){
      const int db = wo + m*16 + rg*4;
      const float b0 = bias[db], b1 = bias[db+1], b2 = bias[db+2], b3 = bias[db+3];
#pragma unroll
      for (int nf = 0; nf < 4; ++nf){
        const int n = n0 + nf*16 + col;
        f32x4 a = acc[m][nf];
        uint2 hv = {cvtpk(elu1(a[0]+b0), elu1(a[1]+b1)),
                    cvtpk(elu1(a[2]+b2), elu1(a[3]+b3))};
        *(uint2*)(qt + ((size_t)b*N_ + n)*D_ + db) = hv;
      }
    }
  } else {
    // k half -> kbuf[b][d][n]
#pragma unroll
    for (int m = 0; m < 2; ++m)
#pragma unroll
      for (int j = 0; j < 4; ++j){
        const int d = wo - 128 + m*16 + rg*4 + j;
        const float bb = bias[128 + d];
#pragma unroll
        for (int nf = 0; nf < 4; ++nf){
          const int n = n0 + nf*16 + col;
          kbuf[((size_t)b*D_ + d)*N_ + n] = f2bf(elu1(acc[m][nf][j] + bb));
        }
      }
  }
}

// ---------------------------------------------------------------------------
// K2: kv partials = sum_n k[d][n]*x[c][n] over K-split. M=128(d) x BN=256(c)
// x K=448(n). 512 threads / 8 waves. Partials stored [c][d]. Fuses kmean.
// (EXACT round-7/15 proven version.)
// ---------------------------------------------------------------------------
__global__ __launch_bounds__(512) void k2_kv(
    const unsigned short* __restrict__ kbuf, const float* __restrict__ x,
    unsigned short* __restrict__ kvp, float* __restrict__ kmp)
{
  __shared__ __align__(16) char Al[128*64];  // [128 d][32 n]
  __shared__ __align__(16) char Bl[256*64];  // [256 c][32 n]
  const int tid = threadIdx.x, lane = tid & 63, wid = tid >> 6;  // 8 waves
  const int ks = blockIdx.x;
  const int b  = blockIdx.y;
  const unsigned short* kb = kbuf + (size_t)b*D_*N_ + ks*KRANGE;
  const float* xb = x + (size_t)b*C_*N_ + ks*KRANGE;
  const int wd = (wid >> 2)*64, wc = (wid & 3)*64;
  f32x4 acc[4][4] = {};
  float kms = 0.f;
  const int sr = tid >> 2, sg = tid & 3;     // staging/kms row & unit

  for (int t = 0; t < KRANGE/32; ++t){
    __syncthreads();
    // A: 128 rows x 4 units = 512 slots, one global_load_lds per thread
    {
      const int u = sg ^ swz4(sr);
      const unsigned short* ga = kb + (size_t)sr*N_ + t*32 + u*8;
      char* lb = Al + (wid*64)*16;           // wave-uniform base; unit = tid
      __builtin_amdgcn_global_load_lds(
          (__attribute__((address_space(1))) void*)ga,
          (__attribute__((address_space(3))) void*)lb, 16, 0, 0);
    }
    // B: x[c][n] fp32 -> bf16 (cvt_pk); 256 rows x 32 n, 16 elems/thread
#pragma unroll
    for (int q = 0; q < 4; ++q){
      int idx = q*512 + tid;                 // 0..2047
      int cc = idx >> 3, n4 = (idx & 7)*4;
      float4 v = *(const float4*)(xb + (size_t)cc*N_ + t*32 + n4);
      uint2 h = {cvtpk(v.x, v.y), cvtpk(v.z, v.w)};
      *(uint2*)(Bl + cc*64 + ((n4*2) ^ (swz4(cc) << 4))) = h;
    }
    __syncthreads();
    s16x8 af[4], bv[4];
#pragma unroll
    for (int m = 0; m < 4; ++m)  af[m] = ldsfrag(Al, wd + m*16 + (lane & 15), lane >> 4);
#pragma unroll
    for (int cf = 0; cf < 4; ++cf) bv[cf] = ldsfrag(Bl, wc + cf*16 + (lane & 15), lane >> 4);
#pragma unroll
    for (int m = 0; m < 4; ++m)
#pragma unroll
      for (int cf = 0; cf < 4; ++cf)
        acc[m][cf] = __builtin_amdgcn_mfma_f32_16x16x32_bf16(af[m], bv[cf], acc[m][cf], 0, 0, 0);
    // kmean partial: thread (sr, sg) sums unit sg of k-row sr (8 bf16)
    {
      uint2 u = *(const uint2*)(Al + sr*64 + ((sg ^ swz4(sr)) << 4));
      uint2 u2 = *(const uint2*)(Al + sr*64 + ((sg ^ swz4(sr)) << 4) + 8);
      const unsigned ua[4] = {u.x, u.y, u2.x, u2.y};
#pragma unroll
      for (int i = 0; i < 4; ++i){
        kms += bf2f((unsigned short)(ua[i] & 0xffffu));
        kms += bf2f((unsigned short)(ua[i] >> 16));
      }
    }
  }

  kms += __shfl_xor(kms, 1);
  kms += __shfl_xor(kms, 2);
  if ((tid & 3) == 0) kmp[((size_t)b*KSPLIT + ks)*D_ + sr] = kms;

  const int col = lane & 15, rg = lane >> 4;
#pragma unroll
  for (int m = 0; m < 4; ++m){
    const int d0 = wd + m*16 + rg*4;
#pragma unroll
    for (int cf = 0; cf < 4; ++cf){
      const int c = wc + cf*16 + col;
      ushort4 hv = {f2bf(acc[m][cf][0]), f2bf(acc[m][cf][1]),
                    f2bf(acc[m][cf][2]), f2bf(acc[m][cf][3])};
      *(ushort4*)(kvp + (((size_t)b*KSPLIT + ks)*C_ + c)*D_ + d0) = hv;
    }
  }
}

// ---------------------------------------------------------------------------
// KR: kvt[b][c][d] = (1/N) * sum_ks kvp[b][ks][c][d]; km[b][d] from kmp.
// (EXACT round-7 version — proven.)
// ---------------------------------------------------------------------------
__global__ __launch_bounds__(256) void kr_reduce(
    const unsigned short* __restrict__ kvp, const float* __restrict__ kmp,
    unsigned short* __restrict__ kvt, float* __restrict__ km)
{
  const int tid = threadIdx.x;
  const int bx = blockIdx.x, b = blockIdx.y;
  const float sc = 1.0f/(float)N_;
#pragma unroll
  for (int it = 0; it < 2; ++it){
    const int idx = (bx*2 + it)*256 + tid;      // 0..4095
    const int c = idx >> 4, dq = (idx & 15)*8;
    float s[8] = {};
    for (int ks = 0; ks < KSPLIT; ++ks){
      u16x8 v = *(const u16x8*)(kvp + (((size_t)b*KSPLIT + ks)*C_ + c)*D_ + dq);
#pragma unroll
      for (int i = 0; i < 8; ++i) s[i] += bf2f(v[i]);
    }
    u16x8 h;
#pragma unroll
    for (int i = 0; i < 8; ++i) h[i] = f2bf(s[i]*sc);
    *(u16x8*)(kvt + ((size_t)b*C_ + c)*D_ + dq) = h;
  }
  if (bx == 0 && tid < D_){
    float s = 0.f;
    for (int ks = 0; ks < KSPLIT; ++ks) s += kmp[((size_t)b*KSPLIT + ks)*D_ + tid];
    km[b*D_ + tid] = s*sc;
  }
}

// ---------------------------------------------------------------------------
// K3: attn[c][n] = (sum_d kvt[c][d]*qt[n][d]) / (q.km + 1e-6), bf16 out.
// (EXACT round-7 version — proven.)
// ---------------------------------------------------------------------------
__global__ __launch_bounds__(256) void k3_attn(
    const unsigned short* __restrict__ qt, const unsigned short* __restrict__ kvt,
    const float* __restrict__ km, unsigned short* __restrict__ attn)
{
  __shared__ __align__(16) char SM[256*64 + 64*64];  // 20KB
  char* Al = SM;                                 // [256 c][32 d] (16KB)
  char* Bl = SM + 256*64;                        // [64 n][32 d]  (4KB)
  unsigned short* P = (unsigned short*)SM;       // [128][72] bf16 (18KB overlay)
  __shared__ float kms[128];
  __shared__ float dens[64];
  const int tid = threadIdx.x, lane = tid & 63, wid = tid >> 6;
  const int n0 = blockIdx.x * 64;
  const int b  = blockIdx.y;
  if (tid < 128) kms[tid] = km[b*D_ + tid];
  const unsigned short* kvb = kvt + (size_t)b*C_*D_;
  const unsigned short* qtb = qt + ((size_t)b*N_ + n0)*D_;
  const int wc = wid*64;
  f32x4 acc[4][4] = {};
  float den = 0.f;

  for (int k0 = 0; k0 < D_; k0 += 32){
    __syncthreads();
    stage_glds<256>(kvb + k0, D_, Al);
    stage_glds<64>(qtb + k0, D_, Bl);
    __syncthreads();
    s16x8 af[4], bv4[4];
#pragma unroll
    for (int m = 0; m < 4; ++m)  af[m]  = ldsfrag(Al, wc + m*16 + (lane & 15), lane >> 4);
#pragma unroll
    for (int nf = 0; nf < 4; ++nf) bv4[nf] = ldsfrag(Bl, nf*16 + (lane & 15), lane >> 4);
#pragma unroll
    for (int m = 0; m < 4; ++m)
#pragma unroll
      for (int nf = 0; nf < 4; ++nf)
        acc[m][nf] = __builtin_amdgcn_mfma_f32_16x16x32_bf16(af[m], bv4[nf], acc[m][nf], 0, 0, 0);
    {
      const int nr = tid >> 2, g = tid & 3;
      uint4 u = *(const uint4*)(Bl + nr*64 + ((g ^ swz4(nr)) << 4));
      const float* kp = kms + k0 + g*8;
      const unsigned ua[4] = {u.x, u.y, u.z, u.w};
#pragma unroll
      for (int i = 0; i < 4; ++i){
        den += bf2f((unsigned short)(ua[i] & 0xffffu)) * kp[i*2];
        den += bf2f((unsigned short)(ua[i] >> 16))     * kp[i*2 + 1];
      }
    }
  }
  den += __shfl_xor(den, 1);
  den += __shfl_xor(den, 2);
  if ((tid & 3) == 0) dens[tid >> 2] = den;
  __syncthreads();   // GEMM LDS reads done + dens visible

  const int col = lane & 15, rg = lane >> 4;
  float rdv[4];
#pragma unroll
  for (int nf = 0; nf < 4; ++nf)
    rdv[nf] = 1.0f / (dens[nf*16 + col] + 1e-6f);

#pragma unroll
  for (int h = 0; h < 2; ++h){
    if ((wid >> 1) == h){
      const int lc = wc - h*128;   // 0 or 64
#pragma unroll
      for (int m = 0; m < 4; ++m)
#pragma unroll
        for (int nf = 0; nf < 4; ++nf)
#pragma unroll
          for (int j = 0; j < 4; ++j)
            P[(lc + m*16 + rg*4 + j)*72 + (nf*16 + col)] = f2bf(acc[m][nf][j] * rdv[nf]);
    }
    __syncthreads();
#pragma unroll
    for (int p = 0; p < 4; ++p){
      const int c = (tid >> 3) + p*32, ch = tid & 7;
      u16x8 v = *(const u16x8*)(P + c*72 + ch*8);
      *(u16x8*)(attn + ((size_t)b*C_ + h*128 + c)*N_ + n0 + ch*8) = v;
    }
    __syncthreads();
  }
}

// ---------------------------------------------------------------------------
// K4: out = attn + depthwise3x3(x) + pe_b. Plane per block, 4-wide along w,
// zero-padded top/bottom LDS rows. x fp32 (EXACT round-7 proven path).
// ---------------------------------------------------------------------------
__global__ __launch_bounds__(256) void k4_pe(
    const float* __restrict__ x, const unsigned short* __restrict__ attn,
    const float* __restrict__ pw, const float* __restrict__ pb,
    float* __restrict__ out)
{
  __shared__ float xs_raw[58*56 + 8];
  float* xs = xs_raw + 4;          // slack so xs[-1] stays in-bounds
  const int tid = threadIdx.x;
  const int ch = blockIdx.x, b = blockIdx.y;
  if (tid < 14)      ((float4*)xs)[tid] = (float4){0.f,0.f,0.f,0.f};        // pad row 0
  else if (tid < 28) ((float4*)xs)[784 + tid] = (float4){0.f,0.f,0.f,0.f};  // pad row 57
  const float* xp = x + ((size_t)b*C_ + ch)*N_;
  for (int i = tid; i < 784; i += 256)
    ((float4*)xs)[14 + i] = ((const float4*)xp)[i];
  const float* wp = pw + ch*9;
  float wgt[9];
#pragma unroll
  for (int i = 0; i < 9; ++i) wgt[i] = wp[i];
  const float bias = pb[ch];
  __syncthreads();
  const unsigned short* ap = attn + ((size_t)b*C_ + ch)*N_;
  float* op = out + ((size_t)b*C_ + ch)*N_;
  for (int u = tid; u < 784; u += 256) {
    const int row = u / 14, g = u - row*14;     // output row, float4 group
    float o0 = bias, o1 = bias, o2 = bias, o3 = bias;
#pragma unroll
    for (int rr = 0; rr < 3; ++rr){
      const float* rp = xs + (row + rr)*56 + g*4;   // padded rows row..row+2
      float4 cv = *(const float4*)rp;
      float lf = (g > 0)  ? rp[-1] : 0.f;
      float rt = (g < 13) ? rp[4]  : 0.f;
      const float wl = wgt[rr*3], wc_ = wgt[rr*3+1], wr = wgt[rr*3+2];
      o0 += wl*lf   + wc_*cv.x + wr*cv.y;
      o1 += wl*cv.x + wc_*cv.y + wr*cv.z;
      o2 += wl*cv.y + wc_*cv.z + wr*cv.w;
      o3 += wl*cv.z + wc_*cv.w + wr*rt;
    }
    ushort4 av = *(const ushort4*)(ap + u*4);
    float4 ov = {o0 + bf2f(av.x), o1 + bf2f(av.y), o2 + bf2f(av.z), o3 + bf2f(av.w)};
    *(float4*)(op + u*4) = ov;
  }
}

extern "C" void kernel_launch(void* const* d_in, const int* in_sizes, int n_in,
                              void* d_out, int out_size, void* d_ws, size_t ws_size,
                              hipStream_t stream) {
  (void)in_sizes; (void)n_in; (void)out_size; (void)ws_size;
  const float* x   = (const float*)d_in[0];
  const float* qkw = (const float*)d_in[1];
  const float* qkb = (const float*)d_in[2];
  const float* pew = (const float*)d_in[3];
  const float* peb = (const float*)d_in[4];
  float* out = (float*)d_out;

  // ws layout (104.9 MB footprint, proven since round 7). slot0 (51.4 MB)
  // hosts kvp+kmp (k2->kr) then attn (k3->k4). kvt slot hosts wb then kvt.
  unsigned short* slot0 = (unsigned short*)d_ws;                // 51.4 MB scratch
  unsigned short* kbuf = slot0 + (size_t)B_*N_*C_;              // [B][128][N] bf16
  unsigned short* qt   = kbuf + (size_t)B_*D_*N_;               // [B][N][128] bf16
  unsigned short* kvt  = qt   + (size_t)B_*N_*D_;               // [B][256][128] bf16
  float* km  = (float*)(kvt + (size_t)B_*C_*D_);                // [B][128] f32
  unsigned short* wb   = kvt;                                   // [256][256] bf16 (alias)
  unsigned short* kvp  = slot0;                                 // [B][7][256][128] bf16 (alias)
  float* kmp = (float*)(kvp + (size_t)B_*KSPLIT*C_*D_);         // [B][7][128] f32 (in slot0)
  unsigned short* attn = slot0;                                 // [B][256][N] bf16 (alias)

  k0_w     <<<dim3(64),          256, 0, stream>>>(qkw, wb);
  k1_qk    <<<dim3(N_/64, B_),   512, 0, stream>>>(x, wb, qkb, kbuf, qt);
  k2_kv    <<<dim3(KSPLIT, B_),  512, 0, stream>>>(kbuf, x, kvp, kmp);
  kr_reduce<<<dim3(8, B_),       256, 0, stream>>>(kvp, kmp, kvt, km);
  k3_attn  <<<dim3(N_/64, B_),   256, 0, stream>>>(qt, kvt, km, attn);
  k4_pe    <<<dim3(C_, B_),      256, 0, stream>>>(x, attn, pew, peb, out);
}

// Round 19
// 150.176 us; speedup vs baseline: 1.0966x; 1.0153x over previous
//
#include <hip/hip_runtime.h>

#define B_ 32
#define C_ 256
#define D_ 128
#define HH 56
#define WW 56
#define N_ 3136
#define KSPLIT 7
#define KRANGE 448   // n per K-split in k2: 14 steps of 32

typedef float f32x4 __attribute__((ext_vector_type(4)));
typedef short s16x8 __attribute__((ext_vector_type(8)));
typedef unsigned short u16x8 __attribute__((ext_vector_type(8)));

// Row swizzle for [R][32-bf16] LDS tiles (64B rows = 4x16B units).
__device__ __forceinline__ int swz4(int r){
  return (r & 3) ^ (((r >> 2) & 1) << 1) ^ ((r >> 3) & 1);
}
__device__ __forceinline__ unsigned short f2bf(float f){
  unsigned u = __float_as_uint(f);
  u += 0x7fffu + ((u >> 16) & 1u);           // RNE
  return (unsigned short)(u >> 16);
}
__device__ __forceinline__ float bf2f(unsigned short h){
  return __uint_as_float(((unsigned)h) << 16);
}
__device__ __forceinline__ float elu1(float v){
  return v > 0.f ? v + 1.f : __expf(v);      // elu(v)+1
}
// HW packed f32x2 -> bf16x2 (RNE), 1 instr for 2 values.
__device__ __forceinline__ unsigned cvtpk(float lo, float hi){
  unsigned r;
  asm("v_cvt_pk_bf16_f32 %0, %1, %2" : "=v"(r) : "v"(lo), "v"(hi));
  return r;
}

// Stage [R rows][32 bf16] bf16-global -> swizzled LDS via global_load_lds.
// 256-thread variant.
template<int R>
__device__ __forceinline__ void stage_glds(const unsigned short* gp, int ld, char* lds){
  const int tid = threadIdx.x;
  const int wid = tid >> 6;
#pragma unroll
  for (int q = 0; q < R/64; ++q){
    const int slot = q*256 + tid;            // = r*4 + unit
    const int r = slot >> 2, gi = slot & 3;
    const int u = gi ^ swz4(r);
    const unsigned short* ga = gp + r*ld + u*8;
    char* lb = lds + (q*256 + wid*64)*16;    // wave-uniform LDS base
    __builtin_amdgcn_global_load_lds(
        (__attribute__((address_space(1))) void*)ga,
        (__attribute__((address_space(3))) void*)lb, 16, 0, 0);
  }
}

// 512-thread variant (one 16B DMA per thread covers 128 rows).
template<int R>
__device__ __forceinline__ void stage_glds512(const unsigned short* gp, int ld, char* lds){
  const int tid = threadIdx.x;
  const int wid = tid >> 6;
#pragma unroll
  for (int q = 0; q < R/128; ++q){
    const int slot = q*512 + tid;            // = r*4 + unit
    const int r = slot >> 2, gi = slot & 3;
    const int u = gi ^ swz4(r);
    const unsigned short* ga = gp + r*ld + u*8;
    char* lb = lds + (q*512 + wid*64)*16;    // wave-uniform LDS base
    __builtin_amdgcn_global_load_lds(
        (__attribute__((address_space(1))) void*)ga,
        (__attribute__((address_space(3))) void*)lb, 16, 0, 0);
  }
}

__device__ __forceinline__ s16x8 ldsfrag(const char* lds, int r, int g){
  return *(const s16x8*)(lds + r*64 + ((g ^ swz4(r)) << 4));
}

// ---------------------------------------------------------------------------
// K0w: W fp32 -> bf16.
// ---------------------------------------------------------------------------
__global__ __launch_bounds__(256) void k0_w(
    const float* __restrict__ w, unsigned short* __restrict__ wb)
{
  const int i = blockIdx.x*256 + threadIdx.x;   // 16384 float4s
  float4 v = *(const float4*)(w + (size_t)i*4);
  uint2 h = {cvtpk(v.x, v.y), cvtpk(v.z, v.w)};
  *(uint2*)(wb + (size_t)i*4) = h;
}

// ---------------------------------------------------------------------------
// K1 v5: qk = elu(W.x + b)+1.  MFMA GEMM M=256(o) x BN=64(n) x K=256(c).
// GEMM loop = EXACT r16 (512t, single-buffer, 2 barriers — 64us across all
// staging variants, so staging isn't the limiter). NEW: epilogue stages
// results in LDS (Pq[64n][136d], Pk[128d][72n], overlaying GEMM tiles after
// a barrier — k3's proven pattern) then writes qt/kbuf as consecutive u16x8
// segments (full 128-256B lines). Theory: old epilogue emitted ~4M 8-32B
// write transactions (4-8x amplification) — the invariant ~40us cost that
// no staging rework touched. Values bit-identical (same f2bf(elu1(.))).
// ---------------------------------------------------------------------------
__global__ __launch_bounds__(512) void k1_qk(
    const float* __restrict__ x, const unsigned short* __restrict__ wb,
    const float* __restrict__ bias,
    unsigned short* __restrict__ kbuf, unsigned short* __restrict__ qt)
{
  __shared__ __align__(16) char SM[64*136*2 + 128*72*2];  // 35.8KB
  char* Al = SM;                             // [256 o][32 c] bf16 (16KB)
  char* Bl = SM + 256*64;                    // [64 n][32 c]  bf16 (4KB)
  unsigned short* Pq = (unsigned short*)SM;              // [64][136] overlay
  unsigned short* Pk = (unsigned short*)(SM + 64*136*2); // [128][72] overlay
  const int tid = threadIdx.x, lane = tid & 63, wid = tid >> 6;
  const int n0 = blockIdx.x * 64;
  const int b  = blockIdx.y;
  const float* xb = x + (size_t)b*C_*N_;
  const int wo = wid*32;
  f32x4 acc[2][4] = {};
  const int cc = tid >> 4;            // 0..31 (c within K-step)
  const int nn = (tid & 15)*4;        // 0..60 (n within tile)

  for (int k0 = 0; k0 < C_; k0 += 32){
    // B tile load (x fp32, coalesced): issue BEFORE barrier to overlap MFMA
    float4 xv = *(const float4*)(xb + (size_t)(k0 + cc)*N_ + n0 + nn);
    __syncthreads();               // previous iteration's LDS reads done
    stage_glds512<256>(wb + k0, C_, Al);
    // transpose scatter: Bl[n][c] bf16, swz4 row swizzle (r2-proven)
    {
      const float vv[4] = {xv.x, xv.y, xv.z, xv.w};
#pragma unroll
      for (int i = 0; i < 4; ++i){
        const int r = nn + i;
        *(unsigned short*)(Bl + r*64 + ((cc*2) ^ (swz4(r) << 4))) = f2bf(vv[i]);
      }
    }
    __syncthreads();               // DMA + scatter visible
    s16x8 af[2], bv4[4];
#pragma unroll
    for (int m = 0; m < 2; ++m)  af[m]  = ldsfrag(Al, wo + m*16 + (lane & 15), lane >> 4);
#pragma unroll
    for (int nf = 0; nf < 4; ++nf) bv4[nf] = ldsfrag(Bl, nf*16 + (lane & 15), lane >> 4);
#pragma unroll
    for (int m = 0; m < 2; ++m)
#pragma unroll
      for (int nf = 0; nf < 4; ++nf)
        acc[m][nf] = __builtin_amdgcn_mfma_f32_16x16x32_bf16(af[m], bv4[nf], acc[m][nf], 0, 0, 0);
  }

  const int col = lane & 15, rg = lane >> 4;
  __syncthreads();   // all GEMM-tile LDS reads retired; safe to overlay
  if (wid < 4){
    // q half -> Pq[n][d]
#pragma unroll
    for (int m = 0; m < 2; ++m){
      const int db = wo + m*16 + rg*4;
      const float b0 = bias[db], b1 = bias[db+1], b2 = bias[db+2], b3 = bias[db+3];
#pragma unroll
      for (int nf = 0; nf < 4; ++nf){
        const int nl = nf*16 + col;
        f32x4 a = acc[m][nf];
        unsigned short* p = Pq + nl*136 + db;
        p[0] = f2bf(elu1(a[0]+b0)); p[1] = f2bf(elu1(a[1]+b1));
        p[2] = f2bf(elu1(a[2]+b2)); p[3] = f2bf(elu1(a[3]+b3));
      }
    }
  } else {
    // k half -> Pk[d][n]
#pragma unroll
    for (int m = 0; m < 2; ++m)
#pragma unroll
      for (int j = 0; j < 4; ++j){
        const int dl = wo - 128 + m*16 + rg*4 + j;
        const float bb = bias[128 + dl];
#pragma unroll
        for (int nf = 0; nf < 4; ++nf)
          Pk[dl*72 + nf*16 + col] = f2bf(elu1(acc[m][nf][j] + bb));
      }
  }
  __syncthreads();

  // coalesced stores: qt rows (64 x 16 segs), kbuf rows (128 x 8 segs)
#pragma unroll
  for (int e = 0; e < 2; ++e){
    const int idx = tid*2 + e;
    { // qt
      const int row = idx >> 4, seg = idx & 15;
      u16x8 v = *(const u16x8*)(Pq + row*136 + seg*8);
      *(u16x8*)(qt + ((size_t)b*N_ + n0 + row)*D_ + seg*8) = v;
    }
    { // kbuf
      const int row = idx >> 3, seg = idx & 7;
      u16x8 v = *(const u16x8*)(Pk + row*72 + seg*8);
      *(u16x8*)(kbuf + ((size_t)b*D_ + row)*N_ + n0 + seg*8) = v;
    }
  }
}

// ---------------------------------------------------------------------------
// K2: kv partials = sum_n k[d][n]*x[c][n] over K-split. M=128(d) x BN=256(c)
// x K=448(n). 512 threads / 8 waves. Partials stored [c][d]. Fuses kmean.
// (EXACT round-7/15 proven version.)
// ---------------------------------------------------------------------------
__global__ __launch_bounds__(512) void k2_kv(
    const unsigned short* __restrict__ kbuf, const float* __restrict__ x,
    unsigned short* __restrict__ kvp, float* __restrict__ kmp)
{
  __shared__ __align__(16) char Al[128*64];  // [128 d][32 n]
  __shared__ __align__(16) char Bl[256*64];  // [256 c][32 n]
  const int tid = threadIdx.x, lane = tid & 63, wid = tid >> 6;  // 8 waves
  const int ks = blockIdx.x;
  const int b  = blockIdx.y;
  const unsigned short* kb = kbuf + (size_t)b*D_*N_ + ks*KRANGE;
  const float* xb = x + (size_t)b*C_*N_ + ks*KRANGE;
  const int wd = (wid >> 2)*64, wc = (wid & 3)*64;
  f32x4 acc[4][4] = {};
  float kms = 0.f;
  const int sr = tid >> 2, sg = tid & 3;     // staging/kms row & unit

  for (int t = 0; t < KRANGE/32; ++t){
    __syncthreads();
    // A: 128 rows x 4 units = 512 slots, one global_load_lds per thread
    {
      const int u = sg ^ swz4(sr);
      const unsigned short* ga = kb + (size_t)sr*N_ + t*32 + u*8;
      char* lb = Al + (wid*64)*16;           // wave-uniform base; unit = tid
      __builtin_amdgcn_global_load_lds(
          (__attribute__((address_space(1))) void*)ga,
          (__attribute__((address_space(3))) void*)lb, 16, 0, 0);
    }
    // B: x[c][n] fp32 -> bf16 (cvt_pk); 256 rows x 32 n, 16 elems/thread
#pragma unroll
    for (int q = 0; q < 4; ++q){
      int idx = q*512 + tid;                 // 0..2047
      int cc = idx >> 3, n4 = (idx & 7)*4;
      float4 v = *(const float4*)(xb + (size_t)cc*N_ + t*32 + n4);
      uint2 h = {cvtpk(v.x, v.y), cvtpk(v.z, v.w)};
      *(uint2*)(Bl + cc*64 + ((n4*2) ^ (swz4(cc) << 4))) = h;
    }
    __syncthreads();
    s16x8 af[4], bv[4];
#pragma unroll
    for (int m = 0; m < 4; ++m)  af[m] = ldsfrag(Al, wd + m*16 + (lane & 15), lane >> 4);
#pragma unroll
    for (int cf = 0; cf < 4; ++cf) bv[cf] = ldsfrag(Bl, wc + cf*16 + (lane & 15), lane >> 4);
#pragma unroll
    for (int m = 0; m < 4; ++m)
#pragma unroll
      for (int cf = 0; cf < 4; ++cf)
        acc[m][cf] = __builtin_amdgcn_mfma_f32_16x16x32_bf16(af[m], bv[cf], acc[m][cf], 0, 0, 0);
    // kmean partial: thread (sr, sg) sums unit sg of k-row sr (8 bf16)
    {
      uint2 u = *(const uint2*)(Al + sr*64 + ((sg ^ swz4(sr)) << 4));
      uint2 u2 = *(const uint2*)(Al + sr*64 + ((sg ^ swz4(sr)) << 4) + 8);
      const unsigned ua[4] = {u.x, u.y, u2.x, u2.y};
#pragma unroll
      for (int i = 0; i < 4; ++i){
        kms += bf2f((unsigned short)(ua[i] & 0xffffu));
        kms += bf2f((unsigned short)(ua[i] >> 16));
      }
    }
  }

  kms += __shfl_xor(kms, 1);
  kms += __shfl_xor(kms, 2);
  if ((tid & 3) == 0) kmp[((size_t)b*KSPLIT + ks)*D_ + sr] = kms;

  const int col = lane & 15, rg = lane >> 4;
#pragma unroll
  for (int m = 0; m < 4; ++m){
    const int d0 = wd + m*16 + rg*4;
#pragma unroll
    for (int cf = 0; cf < 4; ++cf){
      const int c = wc + cf*16 + col;
      ushort4 hv = {f2bf(acc[m][cf][0]), f2bf(acc[m][cf][1]),
                    f2bf(acc[m][cf][2]), f2bf(acc[m][cf][3])};
      *(ushort4*)(kvp + (((size_t)b*KSPLIT + ks)*C_ + c)*D_ + d0) = hv;
    }
  }
}

// ---------------------------------------------------------------------------
// KR: kvt[b][c][d] = (1/N) * sum_ks kvp[b][ks][c][d]; km[b][d] from kmp.
// (EXACT round-7 version — proven.)
// ---------------------------------------------------------------------------
__global__ __launch_bounds__(256) void kr_reduce(
    const unsigned short* __restrict__ kvp, const float* __restrict__ kmp,
    unsigned short* __restrict__ kvt, float* __restrict__ km)
{
  const int tid = threadIdx.x;
  const int bx = blockIdx.x, b = blockIdx.y;
  const float sc = 1.0f/(float)N_;
#pragma unroll
  for (int it = 0; it < 2; ++it){
    const int idx = (bx*2 + it)*256 + tid;      // 0..4095
    const int c = idx >> 4, dq = (idx & 15)*8;
    float s[8] = {};
    for (int ks = 0; ks < KSPLIT; ++ks){
      u16x8 v = *(const u16x8*)(kvp + (((size_t)b*KSPLIT + ks)*C_ + c)*D_ + dq);
#pragma unroll
      for (int i = 0; i < 8; ++i) s[i] += bf2f(v[i]);
    }
    u16x8 h;
#pragma unroll
    for (int i = 0; i < 8; ++i) h[i] = f2bf(s[i]*sc);
    *(u16x8*)(kvt + ((size_t)b*C_ + c)*D_ + dq) = h;
  }
  if (bx == 0 && tid < D_){
    float s = 0.f;
    for (int ks = 0; ks < KSPLIT; ++ks) s += kmp[((size_t)b*KSPLIT + ks)*D_ + tid];
    km[b*D_ + tid] = s*sc;
  }
}

// ---------------------------------------------------------------------------
// K3: attn[c][n] = (sum_d kvt[c][d]*qt[n][d]) / (q.km + 1e-6), bf16 out.
// (EXACT round-7 version — proven.)
// ---------------------------------------------------------------------------
__global__ __launch_bounds__(256) void k3_attn(
    const unsigned short* __restrict__ qt, const unsigned short* __restrict__ kvt,
    const float* __restrict__ km, unsigned short* __restrict__ attn)
{
  __shared__ __align__(16) char SM[256*64 + 64*64];  // 20KB
  char* Al = SM;                                 // [256 c][32 d] (16KB)
  char* Bl = SM + 256*64;                        // [64 n][32 d]  (4KB)
  unsigned short* P = (unsigned short*)SM;       // [128][72] bf16 (18KB overlay)
  __shared__ float kms[128];
  __shared__ float dens[64];
  const int tid = threadIdx.x, lane = tid & 63, wid = tid >> 6;
  const int n0 = blockIdx.x * 64;
  const int b  = blockIdx.y;
  if (tid < 128) kms[tid] = km[b*D_ + tid];
  const unsigned short* kvb = kvt + (size_t)b*C_*D_;
  const unsigned short* qtb = qt + ((size_t)b*N_ + n0)*D_;
  const int wc = wid*64;
  f32x4 acc[4][4] = {};
  float den = 0.f;

  for (int k0 = 0; k0 < D_; k0 += 32){
    __syncthreads();
    stage_glds<256>(kvb + k0, D_, Al);
    stage_glds<64>(qtb + k0, D_, Bl);
    __syncthreads();
    s16x8 af[4], bv4[4];
#pragma unroll
    for (int m = 0; m < 4; ++m)  af[m]  = ldsfrag(Al, wc + m*16 + (lane & 15), lane >> 4);
#pragma unroll
    for (int nf = 0; nf < 4; ++nf) bv4[nf] = ldsfrag(Bl, nf*16 + (lane & 15), lane >> 4);
#pragma unroll
    for (int m = 0; m < 4; ++m)
#pragma unroll
      for (int nf = 0; nf < 4; ++nf)
        acc[m][nf] = __builtin_amdgcn_mfma_f32_16x16x32_bf16(af[m], bv4[nf], acc[m][nf], 0, 0, 0);
    {
      const int nr = tid >> 2, g = tid & 3;
      uint4 u = *(const uint4*)(Bl + nr*64 + ((g ^ swz4(nr)) << 4));
      const float* kp = kms + k0 + g*8;
      const unsigned ua[4] = {u.x, u.y, u.z, u.w};
#pragma unroll
      for (int i = 0; i < 4; ++i){
        den += bf2f((unsigned short)(ua[i] & 0xffffu)) * kp[i*2];
        den += bf2f((unsigned short)(ua[i] >> 16))     * kp[i*2 + 1];
      }
    }
  }
  den += __shfl_xor(den, 1);
  den += __shfl_xor(den, 2);
  if ((tid & 3) == 0) dens[tid >> 2] = den;
  __syncthreads();   // GEMM LDS reads done + dens visible

  const int col = lane & 15, rg = lane >> 4;
  float rdv[4];
#pragma unroll
  for (int nf = 0; nf < 4; ++nf)
    rdv[nf] = 1.0f / (dens[nf*16 + col] + 1e-6f);

#pragma unroll
  for (int h = 0; h < 2; ++h){
    if ((wid >> 1) == h){
      const int lc = wc - h*128;   // 0 or 64
#pragma unroll
      for (int m = 0; m < 4; ++m)
#pragma unroll
        for (int nf = 0; nf < 4; ++nf)
#pragma unroll
          for (int j = 0; j < 4; ++j)
            P[(lc + m*16 + rg*4 + j)*72 + (nf*16 + col)] = f2bf(acc[m][nf][j] * rdv[nf]);
    }
    __syncthreads();
#pragma unroll
    for (int p = 0; p < 4; ++p){
      const int c = (tid >> 3) + p*32, ch = tid & 7;
      u16x8 v = *(const u16x8*)(P + c*72 + ch*8);
      *(u16x8*)(attn + ((size_t)b*C_ + h*128 + c)*N_ + n0 + ch*8) = v;
    }
    __syncthreads();
  }
}

// ---------------------------------------------------------------------------
// K4: out = attn + depthwise3x3(x) + pe_b. Plane per block, 4-wide along w,
// zero-padded top/bottom LDS rows. x fp32 (EXACT round-7 proven path).
// ---------------------------------------------------------------------------
__global__ __launch_bounds__(256) void k4_pe(
    const float* __restrict__ x, const unsigned short* __restrict__ attn,
    const float* __restrict__ pw, const float* __restrict__ pb,
    float* __restrict__ out)
{
  __shared__ float xs_raw[58*56 + 8];
  float* xs = xs_raw + 4;          // slack so xs[-1] stays in-bounds
  const int tid = threadIdx.x;
  const int ch = blockIdx.x, b = blockIdx.y;
  if (tid < 14)      ((float4*)xs)[tid] = (float4){0.f,0.f,0.f,0.f};        // pad row 0
  else if (tid < 28) ((float4*)xs)[784 + tid] = (float4){0.f,0.f,0.f,0.f};  // pad row 57
  const float* xp = x + ((size_t)b*C_ + ch)*N_;
  for (int i = tid; i < 784; i += 256)
    ((float4*)xs)[14 + i] = ((const float4*)xp)[i];
  const float* wp = pw + ch*9;
  float wgt[9];
#pragma unroll
  for (int i = 0; i < 9; ++i) wgt[i] = wp[i];
  const float bias = pb[ch];
  __syncthreads();
  const unsigned short* ap = attn + ((size_t)b*C_ + ch)*N_;
  float* op = out + ((size_t)b*C_ + ch)*N_;
  for (int u = tid; u < 784; u += 256) {
    const int row = u / 14, g = u - row*14;     // output row, float4 group
    float o0 = bias, o1 = bias, o2 = bias, o3 = bias;
#pragma unroll
    for (int rr = 0; rr < 3; ++rr){
      const float* rp = xs + (row + rr)*56 + g*4;   // padded rows row..row+2
      float4 cv = *(const float4*)rp;
      float lf = (g > 0)  ? rp[-1] : 0.f;
      float rt = (g < 13) ? rp[4]  : 0.f;
      const float wl = wgt[rr*3], wc_ = wgt[rr*3+1], wr = wgt[rr*3+2];
      o0 += wl*lf   + wc_*cv.x + wr*cv.y;
      o1 += wl*cv.x + wc_*cv.y + wr*cv.z;
      o2 += wl*cv.y + wc_*cv.z + wr*cv.w;
      o3 += wl*cv.z + wc_*cv.w + wr*rt;
    }
    ushort4 av = *(const ushort4*)(ap + u*4);
    float4 ov = {o0 + bf2f(av.x), o1 + bf2f(av.y), o2 + bf2f(av.z), o3 + bf2f(av.w)};
    *(float4*)(op + u*4) = ov;
  }
}

extern "C" void kernel_launch(void* const* d_in, const int* in_sizes, int n_in,
                              void* d_out, int out_size, void* d_ws, size_t ws_size,
                              hipStream_t stream) {
  (void)in_sizes; (void)n_in; (void)out_size; (void)ws_size;
  const float* x   = (const float*)d_in[0];
  const float* qkw = (const float*)d_in[1];
  const float* qkb = (const float*)d_in[2];
  const float* pew = (const float*)d_in[3];
  const float* peb = (const float*)d_in[4];
  float* out = (float*)d_out;

  // ws layout (104.9 MB footprint, proven since round 7). slot0 (51.4 MB)
  // hosts kvp+kmp (k2->kr) then attn (k3->k4). kvt slot hosts wb then kvt.
  unsigned short* slot0 = (unsigned short*)d_ws;                // 51.4 MB scratch
  unsigned short* kbuf = slot0 + (size_t)B_*N_*C_;              // [B][128][N] bf16
  unsigned short* qt   = kbuf + (size_t)B_*D_*N_;               // [B][N][128] bf16
  unsigned short* kvt  = qt   + (size_t)B_*N_*D_;               // [B][256][128] bf16
  float* km  = (float*)(kvt + (size_t)B_*C_*D_);                // [B][128] f32
  unsigned short* wb   = kvt;                                   // [256][256] bf16 (alias)
  unsigned short* kvp  = slot0;                                 // [B][7][256][128] bf16 (alias)
  float* kmp = (float*)(kvp + (size_t)B_*KSPLIT*C_*D_);         // [B][7][128] f32 (in slot0)
  unsigned short* attn = slot0;                                 // [B][256][N] bf16 (alias)

  k0_w     <<<dim3(64),          256, 0, stream>>>(qkw, wb);
  k1_qk    <<<dim3(N_/64, B_),   512, 0, stream>>>(x, wb, qkb, kbuf, qt);
  k2_kv    <<<dim3(KSPLIT, B_),  512, 0, stream>>>(kbuf, x, kvp, kmp);
  kr_reduce<<<dim3(8, B_),       256, 0, stream>>>(kvp, kmp, kvt, km);
  k3_attn  <<<dim3(N_/64, B_),   256, 0, stream>>>(qt, kvt, km, attn);
  k4_pe    <<<dim3(C_, B_),      256, 0, stream>>>(x, attn, pew, peb, out);
}